// Round 1
// baseline (448.447 us; speedup 1.0000x reference)
//
#include <hip/hip_runtime.h>
#include <math.h>

#define BZc 8
#define Cc 512
#define C2c 256
#define HWc 4096
#define OUTC 768

#define BK 16
#define BM 128
#define BN 128
#define QSTEPS 4   // q-tiles of 128 per chunk -> chunk = 512 q
#define QCH 8      // 8 chunks cover 4096 q

// ---------------- K1: transpose latter -> latT[b][q][c], compute invnorm[b][q] ----
__global__ __launch_bounds__(256) void k_transnorm(const float* __restrict__ x,
                                                   float* __restrict__ latT,
                                                   float* __restrict__ invn) {
    int b  = blockIdx.y;
    int q0 = blockIdx.x * 64;
    int tid = threadIdx.x;
    __shared__ float t[64][65];
    __shared__ float sq[4][64];
    const float* lx = x + ((size_t)b * Cc + C2c) * HWc;   // latter channels
    float* lt = latT + ((size_t)b * HWc + q0) * C2c;
    float sacc = 0.f;
    for (int c0 = 0; c0 < C2c; c0 += 64) {
        for (int i = tid; i < 64 * 64; i += 256) {
            int cc = i >> 6, qq = i & 63;                 // coalesced over qq
            float v = lx[(size_t)(c0 + cc) * HWc + q0 + qq];
            t[qq][cc] = v;
            sacc += v * v;                                 // this thread's qq == tid&63 always
        }
        __syncthreads();
        for (int i = tid; i < 64 * 64; i += 256) {
            int qq = i >> 6, cc = i & 63;                 // coalesced over cc
            lt[(size_t)qq * C2c + c0 + cc] = t[qq][cc];
        }
        __syncthreads();
    }
    sq[tid >> 6][tid & 63] = sacc;
    __syncthreads();
    if (tid < 64) {
        float s = sq[0][tid] + sq[1][tid] + sq[2][tid] + sq[3][tid];
        invn[b * HWc + q0 + tid] = 1.0f / (sqrtf(s) + 1e-8f);
    }
}

// ---------------- K2: fused GEMM (former x latter) + per-chunk argmax ------------
__global__ __launch_bounds__(256) void k_gemm_argmax(const float* __restrict__ x,
                                                     const float* __restrict__ invn,
                                                     const int* __restrict__ mask,
                                                     float* __restrict__ bval,
                                                     int* __restrict__ bidx) {
    int pt  = blockIdx.x;   // 0..7 : 128 masked-p rows each
    int qc  = blockIdx.y;   // 0..7 : 512 q each
    int b   = blockIdx.z;
    int tid = threadIdx.x;
    int tc  = tid & 15, tr = tid >> 4;

    __shared__ float As[BK][BM];
    __shared__ float Bs[BK][BN];

    const float* fx = x + (size_t)b * Cc * HWc;           // former base
    const float* lx = fx + (size_t)C2c * HWc;             // latter base

    float best_v[8];
    int   best_i[8];
#pragma unroll
    for (int i = 0; i < 8; ++i) { best_v[i] = -INFINITY; best_i[i] = 0; }

    for (int qs = 0; qs < QSTEPS; ++qs) {
        int q0 = qc * 512 + qs * 128;
        float acc[8][8];
#pragma unroll
        for (int i = 0; i < 8; ++i)
#pragma unroll
            for (int j = 0; j < 8; ++j) acc[i][j] = 0.f;

        for (int kt = 0; kt < C2c; kt += BK) {
            // stage A: 16x128 (masked-p columns; p runs contiguous by 32)
            for (int i = tid; i < BK * BM; i += 256) {
                int k = i >> 7, m = i & 127;
                int mp = pt * 128 + m;
                int p  = ((16 + (mp >> 5)) << 6) + 16 + (mp & 31);
                As[k][m] = fx[(size_t)(kt + k) * HWc + p];
            }
            // stage B: 16x128, q contiguous
            for (int i = tid; i < BK * BN; i += 256) {
                int k = i >> 7, n = i & 127;
                Bs[k][n] = lx[(size_t)(kt + k) * HWc + q0 + n];
            }
            __syncthreads();
#pragma unroll
            for (int k = 0; k < BK; ++k) {
                float a[8], bb[8];
#pragma unroll
                for (int i = 0; i < 8; ++i) a[i] = As[k][tr * 8 + i];
#pragma unroll
                for (int j = 0; j < 8; ++j) bb[j] = Bs[k][tc * 8 + j];
#pragma unroll
                for (int i = 0; i < 8; ++i)
#pragma unroll
                    for (int j = 0; j < 8; ++j)
                        acc[i][j] = fmaf(a[i], bb[j], acc[i][j]);
            }
            __syncthreads();
        }
        // epilogue: scale by invnorm, mask, running argmax (ascending q, strict >)
#pragma unroll
        for (int j = 0; j < 8; ++j) {
            int q = q0 + tc * 8 + j;
            if (mask[q]) continue;
            float inv = invn[b * HWc + q];
#pragma unroll
            for (int i = 0; i < 8; ++i) {
                float v = acc[i][j] * inv;
                if (v > best_v[i]) { best_v[i] = v; best_i[i] = q; }
            }
        }
    }

    // cross-thread reduction over the 16 column-threads per row (reuse As/Bs)
    float* red_v = &As[0][0];            // 128*16 floats
    int*   red_i = (int*)&Bs[0][0];      // 128*16 ints
    __syncthreads();
#pragma unroll
    for (int i = 0; i < 8; ++i) {
        red_v[(tr * 8 + i) * 16 + tc] = best_v[i];
        red_i[(tr * 8 + i) * 16 + tc] = best_i[i];
    }
    __syncthreads();
    if (tid < 128) {
        float v = -INFINITY; int id = 0;
        for (int t = 0; t < 16; ++t) {           // tc ascending == q ascending
            float vv = red_v[tid * 16 + t];
            int   ii = red_i[tid * 16 + t];
            if (vv > v || (vv == v && ii < id)) { v = vv; id = ii; }
        }
        int mp = pt * 128 + tid;
        bval[((size_t)b * 1024 + mp) * QCH + qc] = v;
        bidx[((size_t)b * 1024 + mp) * QCH + qc] = id;
    }
}

// ---------------- K3: reduce chunks -> final best index --------------------------
__global__ void k_reduce(const float* __restrict__ bval, const int* __restrict__ bidx,
                         int* __restrict__ bfin) {
    int t = blockIdx.x * blockDim.x + threadIdx.x;
    if (t >= BZc * 1024) return;
    float v = -INFINITY; int id = 0;
    for (int qc = 0; qc < QCH; ++qc) {           // chunks ascending q, strict >
        float vv = bval[(size_t)t * QCH + qc];
        int   ii = bidx[(size_t)t * QCH + qc];
        if (vv > v) { v = vv; id = ii; }
    }
    bfin[t] = id;
}

// ---------------- K4: out[:, :512] = x ; out[:, 512:] = 0 ------------------------
__global__ __launch_bounds__(256) void k_fill(const float* __restrict__ x,
                                              float* __restrict__ out) {
    size_t i4 = (size_t)blockIdx.x * blockDim.x + threadIdx.x;
    size_t total4 = (size_t)BZc * OUTC * HWc / 4;
    if (i4 >= total4) return;
    size_t e   = i4 * 4;
    size_t per = (size_t)OUTC * HWc;
    size_t b   = e / per;
    size_t rem = e % per;
    int ch = (int)(rem / HWc);
    float4* o4 = (float4*)out;
    if (ch < Cc) {
        const float4* x4 = (const float4*)x;
        o4[i4] = x4[((size_t)b * Cc * HWc + rem) >> 2];
    } else {
        o4[i4] = make_float4(0.f, 0.f, 0.f, 0.f);
    }
}

// ---------------- K5: gather best latter vectors into shift region ---------------
__global__ __launch_bounds__(256) void k_scatter(const float* __restrict__ latT,
                                                 const int* __restrict__ bfin,
                                                 float* __restrict__ out) {
    int rrow = blockIdx.x;   // 0..31 (image row r = 16+rrow)
    int b    = blockIdx.y;
    int tid  = threadIdx.x;
    __shared__ float tile[32][257];
    __shared__ int bid[32];
    if (tid < 32) bid[tid] = bfin[b * 1024 + rrow * 32 + tid];
    __syncthreads();
    for (int i = tid; i < 32 * 256; i += 256) {
        int pp = i >> 8, c = i & 255;            // coalesced 256-float rows
        tile[pp][c] = latT[((size_t)b * HWc + bid[pp]) * C2c + c];
    }
    __syncthreads();
    int r = 16 + rrow;
    float* ob = out + (size_t)b * OUTC * HWc + (size_t)Cc * HWc;
    for (int i = tid; i < 256 * 32; i += 256) {
        int ch = i >> 5, j = i & 31;             // 32-contiguous-float writes per ch
        ob[(size_t)ch * HWc + (size_t)r * 64 + 16 + j] = tile[j][ch];
    }
}

extern "C" void kernel_launch(void* const* d_in, const int* in_sizes, int n_in,
                              void* d_out, int out_size, void* d_ws, size_t ws_size,
                              hipStream_t stream) {
    const float* x    = (const float*)d_in[0];
    const int*   mask = (const int*)d_in[1];
    float* out = (float*)d_out;
    char*  ws  = (char*)d_ws;

    // workspace layout (~32.7 MiB total)
    float* latT = (float*)(ws);                       // 8*4096*256 f32 = 32 MiB
    float* invn = (float*)(ws + 33554432);            // 8*4096 f32
    float* bval = (float*)(ws + 33685504);            // 8*1024*8 f32
    int*   bidx = (int*)  (ws + 33947648);            // 8*1024*8 i32
    int*   bfin = (int*)  (ws + 34209792);            // 8*1024 i32

    k_transnorm<<<dim3(HWc / 64, BZc), 256, 0, stream>>>(x, latT, invn);
    k_gemm_argmax<<<dim3(8, QCH, BZc), 256, 0, stream>>>(x, invn, mask, bval, bidx);
    k_reduce<<<(BZc * 1024 + 255) / 256, 256, 0, stream>>>(bval, bidx, bfin);
    k_fill<<<(int)(((size_t)BZc * OUTC * HWc / 4 + 255) / 256), 256, 0, stream>>>(x, out);
    k_scatter<<<dim3(32, BZc), 256, 0, stream>>>(latT, bfin, out);
}

// Round 2
// 226.977 us; speedup vs baseline: 1.9757x; 1.9757x over previous
//
#include <hip/hip_runtime.h>
#include <math.h>

#define BZc 8
#define Cc 512
#define C2c 256
#define HWc 4096
#define OUTC 768
#define NP 1024     // masked p count (structural: mask has 1024 ones)
#define NQ 3072     // unmasked q count
#define QT 12       // q tiles of 256
#define PT 8        // p tiles of 128

// ---------------- K0: build compacted index lists from mask ----------------------
__global__ __launch_bounds__(1024) void k_build(const int* __restrict__ mask,
                                                int* __restrict__ pidx,
                                                int* __restrict__ qidx) {
    __shared__ int s0[1024], s1[1024], t0[1024], t1[1024];
    int t = threadIdx.x;
    int f[4];
    int cp = 0;
#pragma unroll
    for (int j = 0; j < 4; ++j) { f[j] = mask[t * 4 + j]; cp += f[j]; }
    s0[t] = cp; s1[t] = 4 - cp;
    __syncthreads();
    int *a = s0, *b = s1, *c = t0, *d = t1;
    for (int off = 1; off < 1024; off <<= 1) {
        int vp = a[t] + (t >= off ? a[t - off] : 0);
        int vq = b[t] + (t >= off ? b[t - off] : 0);
        c[t] = vp; d[t] = vq;
        __syncthreads();
        int* tmp;
        tmp = a; a = c; c = tmp;
        tmp = b; b = d; d = tmp;
    }
    int ep = a[t] - cp;          // exclusive prefix (masked)
    int eq = b[t] - (4 - cp);    // exclusive prefix (unmasked)
#pragma unroll
    for (int j = 0; j < 4; ++j) {
        int idx = t * 4 + j;
        if (f[j]) pidx[ep++] = idx; else qidx[eq++] = idx;
    }
}

// ---------------- K1: transpose latter -> latT[b][q][c], compute invnorm[b][q] ----
__global__ __launch_bounds__(256) void k_transnorm(const float* __restrict__ x,
                                                   float* __restrict__ latT,
                                                   float* __restrict__ invn) {
    int b  = blockIdx.y;
    int q0 = blockIdx.x * 64;
    int tid = threadIdx.x;
    __shared__ float t[64][65];
    __shared__ float sq[4][64];
    const float* lx = x + ((size_t)b * Cc + C2c) * HWc;
    float* lt = latT + ((size_t)b * HWc + q0) * C2c;
    float sacc = 0.f;
    for (int c0 = 0; c0 < C2c; c0 += 64) {
        for (int i = tid; i < 64 * 64; i += 256) {
            int cc = i >> 6, qq = i & 63;
            float v = lx[(size_t)(c0 + cc) * HWc + q0 + qq];
            t[qq][cc] = v;
            sacc += v * v;
        }
        __syncthreads();
        for (int i = tid; i < 64 * 64; i += 256) {
            int qq = i >> 6, cc = i & 63;
            lt[(size_t)qq * C2c + c0 + cc] = t[qq][cc];
        }
        __syncthreads();
    }
    sq[tid >> 6][tid & 63] = sacc;
    __syncthreads();
    if (tid < 64) {
        float s = sq[0][tid] + sq[1][tid] + sq[2][tid] + sq[3][tid];
        invn[b * HWc + q0 + tid] = 1.0f / (sqrtf(s) + 1e-8f);
    }
}

// ---------------- K2: fused GEMM (compacted p x compacted q) + argmax -------------
// 8x16 register tile, BM=128, BN=256, BK=16, register-prefetched staging.
__global__ __launch_bounds__(256, 2) void k_gemm2(const float* __restrict__ x,
                                                  const float* __restrict__ invn,
                                                  const int* __restrict__ pidx,
                                                  const int* __restrict__ qidx,
                                                  float* __restrict__ bval,
                                                  int* __restrict__ bidx) {
    int pt = blockIdx.x, qt = blockIdx.y, b = blockIdx.z;
    int tid = threadIdx.x;
    int tr = tid >> 4, tc = tid & 15;

    __shared__ float As[16][128];   // 8 KB
    __shared__ float Bs[16][256];   // 16 KB

    const float* fx = x + (size_t)b * Cc * HWc;      // former
    const float* lx = fx + (size_t)C2c * HWc;        // latter

    int pm = pidx[pt * 128 + (tid & 127)];           // my staged A column (fixed)
    int qn = qidx[qt * 256 + tid];                   // my staged B column (fixed)

    float ra[8], rb[16];
    // preload ktile 0 into registers
#pragma unroll
    for (int it = 0; it < 8; ++it) { int k = (tid >> 7) + 2 * it; ra[it] = fx[(size_t)k * HWc + pm]; }
#pragma unroll
    for (int it = 0; it < 16; ++it) { rb[it] = lx[(size_t)it * HWc + qn]; }

    float acc[8][16];
#pragma unroll
    for (int i = 0; i < 8; ++i)
#pragma unroll
        for (int j = 0; j < 16; ++j) acc[i][j] = 0.f;

    for (int kt = 0; kt < C2c; kt += 16) {
        __syncthreads();             // previous compute done -> LDS reusable
#pragma unroll
        for (int it = 0; it < 8; ++it) { int k = (tid >> 7) + 2 * it; As[k][tid & 127] = ra[it]; }
#pragma unroll
        for (int it = 0; it < 16; ++it) { Bs[it][tid] = rb[it]; }
        __syncthreads();
        if (kt + 16 < C2c) {         // issue next ktile's loads; they complete under the FMAs
#pragma unroll
            for (int it = 0; it < 8; ++it) {
                int k = kt + 16 + (tid >> 7) + 2 * it;
                ra[it] = fx[(size_t)k * HWc + pm];
            }
#pragma unroll
            for (int it = 0; it < 16; ++it) { rb[it] = lx[(size_t)(kt + 16 + it) * HWc + qn]; }
        }
#pragma unroll 4
        for (int k = 0; k < 16; ++k) {
            float4 a0 = *(const float4*)&As[k][tr * 8];
            float4 a1 = *(const float4*)&As[k][tr * 8 + 4];
            float av[8] = {a0.x, a0.y, a0.z, a0.w, a1.x, a1.y, a1.z, a1.w};
            float4 bv[4];
#pragma unroll
            for (int jj = 0; jj < 4; ++jj) bv[jj] = *(const float4*)&Bs[k][tc * 4 + jj * 64];
#pragma unroll
            for (int i = 0; i < 8; ++i) {
#pragma unroll
                for (int jj = 0; jj < 4; ++jj) {
                    acc[i][jj * 4 + 0] = fmaf(av[i], bv[jj].x, acc[i][jj * 4 + 0]);
                    acc[i][jj * 4 + 1] = fmaf(av[i], bv[jj].y, acc[i][jj * 4 + 1]);
                    acc[i][jj * 4 + 2] = fmaf(av[i], bv[jj].z, acc[i][jj * 4 + 2]);
                    acc[i][jj * 4 + 3] = fmaf(av[i], bv[jj].w, acc[i][jj * 4 + 3]);
                }
            }
        }
    }

    // ---------------- epilogue: scale, per-row argmax, cross-thread reduce --------
    __syncthreads();   // done reading As/Bs as tiles
    float inv_c[16];
#pragma unroll
    for (int jj = 0; jj < 4; ++jj)
#pragma unroll
        for (int v = 0; v < 4; ++v) {
            int nc = qt * 256 + tc * 4 + jj * 64 + v;
            inv_c[jj * 4 + v] = invn[b * HWc + qidx[nc]];
        }
    float best_v[8]; int best_i[8];
#pragma unroll
    for (int i = 0; i < 8; ++i) { best_v[i] = -INFINITY; best_i[i] = 0; }
#pragma unroll
    for (int jj = 0; jj < 4; ++jj)       // ascending ncomp within thread
#pragma unroll
        for (int v = 0; v < 4; ++v) {
            int col = jj * 4 + v;
            int nc = qt * 256 + tc * 4 + jj * 64 + v;
            float iv = inv_c[col];
#pragma unroll
            for (int i = 0; i < 8; ++i) {
                float val = acc[i][col] * iv;
                if (val > best_v[i]) { best_v[i] = val; best_i[i] = nc; }
            }
        }
    float* red_v = &As[0][0];            // 128*16 floats = 8 KB
    int*   red_i = (int*)&Bs[0][0];
#pragma unroll
    for (int i = 0; i < 8; ++i) {
        red_v[(tr * 8 + i) * 16 + tc] = best_v[i];
        red_i[(tr * 8 + i) * 16 + tc] = best_i[i];
    }
    __syncthreads();
    if (tid < 128) {
        float v = -INFINITY; int id = 1 << 30;
        for (int t2 = 0; t2 < 16; ++t2) {
            float vv = red_v[tid * 16 + t2];
            int   ii = red_i[tid * 16 + t2];
            if (vv > v || (vv == v && ii < id)) { v = vv; id = ii; }
        }
        int mp = pt * 128 + tid;
        bval[((size_t)b * NP + mp) * QT + qt] = v;
        bidx[((size_t)b * NP + mp) * QT + qt] = id;
    }
}

// ---------------- K3: reduce chunks -> final best compacted index ----------------
__global__ void k_reduce(const float* __restrict__ bval, const int* __restrict__ bidx,
                         int* __restrict__ bfin) {
    int t = blockIdx.x * blockDim.x + threadIdx.x;
    if (t >= BZc * NP) return;
    float v = -INFINITY; int id = 0;
    for (int qc = 0; qc < QT; ++qc) {    // chunks ascending q, strict >
        float vv = bval[(size_t)t * QT + qc];
        int   ii = bidx[(size_t)t * QT + qc];
        if (vv > v) { v = vv; id = ii; }
    }
    bfin[t] = id;
}

// ---------------- K4: out[:, :512] = x ; out[:, 512:] = 0 ------------------------
__global__ __launch_bounds__(256) void k_fill(const float* __restrict__ x,
                                              float* __restrict__ out) {
    size_t i4 = (size_t)blockIdx.x * blockDim.x + threadIdx.x;
    size_t total4 = (size_t)BZc * OUTC * HWc / 4;
    if (i4 >= total4) return;
    size_t e   = i4 * 4;
    size_t per = (size_t)OUTC * HWc;
    size_t b   = e / per;
    size_t rem = e % per;
    int ch = (int)(rem / HWc);
    float4* o4 = (float4*)out;
    if (ch < Cc) {
        const float4* x4 = (const float4*)x;
        o4[i4] = x4[((size_t)b * Cc * HWc + rem) >> 2];
    } else {
        o4[i4] = make_float4(0.f, 0.f, 0.f, 0.f);
    }
}

// ---------------- K5: gather best latter vectors into shift region ---------------
__global__ __launch_bounds__(256) void k_scatter(const float* __restrict__ latT,
                                                 const int* __restrict__ bfin,
                                                 const int* __restrict__ pidx,
                                                 const int* __restrict__ qidx,
                                                 float* __restrict__ out) {
    int blk = blockIdx.x;   // 0..31 : 32 masked p each
    int b   = blockIdx.y;
    int tid = threadIdx.x;
    __shared__ float tile[32][257];
    __shared__ int qd[32], pd[32];
    if (tid < 32) {
        qd[tid] = qidx[bfin[b * NP + blk * 32 + tid]];
        pd[tid] = pidx[blk * 32 + tid];
    }
    __syncthreads();
    for (int i = tid; i < 32 * 256; i += 256) {
        int pp = i >> 8, c = i & 255;
        tile[pp][c] = latT[((size_t)b * HWc + qd[pp]) * C2c + c];
    }
    __syncthreads();
    float* ob = out + (size_t)b * OUTC * HWc + (size_t)Cc * HWc;
    for (int i = tid; i < 256 * 32; i += 256) {
        int ch = i >> 5, j = i & 31;     // consecutive j -> consecutive p within runs
        ob[(size_t)ch * HWc + pd[j]] = tile[j][ch];
    }
}

extern "C" void kernel_launch(void* const* d_in, const int* in_sizes, int n_in,
                              void* d_out, int out_size, void* d_ws, size_t ws_size,
                              hipStream_t stream) {
    const float* x    = (const float*)d_in[0];
    const int*   mask = (const int*)d_in[1];
    float* out = (float*)d_out;
    char*  ws  = (char*)d_ws;

    // workspace layout (~33 MiB)
    float* latT = (float*)(ws);                       // 8*4096*256 f32 = 32 MiB
    float* invn = (float*)(ws + 33554432);            // 8*4096 f32
    float* bval = (float*)(ws + 33685504);            // 8*1024*12 f32
    int*   bidx = (int*)  (ws + 34078720);            // 8*1024*12 i32
    int*   bfin = (int*)  (ws + 34471936);            // 8*1024 i32
    int*   pidx = (int*)  (ws + 34504704);            // 1024 i32 (padded)
    int*   qidx = (int*)  (ws + 34521088);            // 3072 i32 (padded)

    k_build<<<1, 1024, 0, stream>>>(mask, pidx, qidx);
    k_transnorm<<<dim3(HWc / 64, BZc), 256, 0, stream>>>(x, latT, invn);
    k_gemm2<<<dim3(PT, QT, BZc), 256, 0, stream>>>(x, invn, pidx, qidx, bval, bidx);
    k_reduce<<<(BZc * NP + 255) / 256, 256, 0, stream>>>(bval, bidx, bfin);
    k_fill<<<(int)(((size_t)BZc * OUTC * HWc / 4 + 255) / 256), 256, 0, stream>>>(x, out);
    k_scatter<<<dim3(32, BZc), 256, 0, stream>>>(latT, bfin, pidx, qidx, out);
}